// Round 1
// baseline (193.029 us; speedup 1.0000x reference)
//
#include <hip/hip_runtime.h>

// OverlapPatchEmbed: extract overlapping 16x16 patches, stride 8, from
// x (64, 3, 224, 224) fp32 -> out (64, 729, 3, 256) fp32.
// Pure gather; memory-bound. One thread per output float4.
//
// Block = one (b, patch) pair: 192 threads = 3 waves; thread t:
//   c  = t >> 6        (channel 0..2)
//   q4 = t & 63        (float4 index within the 256-elem patch)
//   r  = q4 >> 2       (patch row 0..15)
//   s  = (q4 & 3) * 4  (patch col, steps of 4)
// Store: out[blockIdx*192 + t]  -> fully coalesced 3 KB per block.
// Load:  x[((b*3+c)*224 + py*8+r)*224 + px*8+s] -- 16B-aligned float4
//        (px*8 multiple of 8, s multiple of 4, W=224 multiple of 4).

constexpr int NB    = 64;    // batch
constexpr int NC    = 3;     // channels
constexpr int HW    = 224;   // height == width
constexpr int PS    = 16;    // patch size
constexpr int ST    = 8;     // stride = patch - overlap
constexpr int NP    = 27;    // patches per dim: (224-16)/8 + 1
constexpr int NPP   = NP * NP;           // 729 patches per image
constexpr int TPB   = NC * (PS * PS / 4); // 192 threads = 3 waves

__global__ __launch_bounds__(TPB) void overlap_patch_kernel(
    const float4* __restrict__ x, float4* __restrict__ out)
{
    const int bp = blockIdx.x;        // b * 729 + p
    const int p  = bp % NPP;
    const int b  = bp / NPP;
    const int py = p / NP;
    const int px = p % NP;

    const int t  = threadIdx.x;
    const int c  = t >> 6;            // 0..2
    const int q4 = t & 63;            // 0..63
    const int r  = q4 >> 2;           // 0..15
    const int s  = (q4 & 3) << 2;     // 0,4,8,12

    const int row = py * ST + r;
    const int col = px * ST + s;
    const long in_elem = ((long)(b * NC + c) * HW + row) * HW + col;

    out[(long)bp * TPB + t] = x[in_elem >> 2];
}

extern "C" void kernel_launch(void* const* d_in, const int* in_sizes, int n_in,
                              void* d_out, int out_size, void* d_ws, size_t ws_size,
                              hipStream_t stream) {
    const float4* x = (const float4*)d_in[0];
    float4* out = (float4*)d_out;
    const int grid = NB * NPP;        // 46656 blocks
    overlap_patch_kernel<<<grid, TPB, 0, stream>>>(x, out);
}

// Round 2
// 173.811 us; speedup vs baseline: 1.1106x; 1.1106x over previous
//
#include <hip/hip_runtime.h>

// OverlapPatchEmbed: x (64,3,224,224) fp32 -> out (64,729,3,256) fp32.
// patch=16, stride=8, n=27 patches/dim.
//
// LDS-staged: block = (b, py, c). Stage the 16-row x 224-col input band
// (14.25 KB, row stride padded to 228 floats for LDS bank floor) with
// coalesced 896B-row loads; then write 27 overlapping patches as 1 KB
// contiguous coalesced stores. Eliminates x-overlap read redundancy
// (4x -> 2x), makes every global access large-contiguous, and gives each
// thread ~10 independent memory ops for latency hiding.

constexpr int NB  = 64;
constexpr int NC  = 3;
constexpr int HWD = 224;
constexpr int PS  = 16;   // patch size
constexpr int ST  = 8;    // stride
constexpr int NP  = 27;   // patches per dim
constexpr int ROW4 = HWD / 4;        // 56 float4 per image row
constexpr int LDSW = 228;            // LDS row stride in floats (+4 pad)
constexpr int TPB  = 256;

__global__ __launch_bounds__(TPB) void overlap_patch_lds(
    const float4* __restrict__ x, float4* __restrict__ out)
{
    // block = (b, py, c)
    const int blk = blockIdx.x;
    const int c   = blk % NC;
    const int tmp = blk / NC;
    const int py  = tmp % NP;
    const int b   = tmp / NP;

    __shared__ float lds[PS * LDSW];   // 14592 B

    const int t = threadIdx.x;

    // Stage 1: load 16 rows x 56 float4 (896 float4), coalesced.
    const int gbase = ((b * NC + c) * HWD + py * ST) * ROW4;  // float4 units
    #pragma unroll
    for (int k = 0; k < 4; ++k) {
        const int j = t + k * TPB;
        if (j < PS * ROW4) {
            const int r    = j / ROW4;
            const int col4 = j - r * ROW4;
            const float4 v = x[gbase + j];
            *(float4*)&lds[r * LDSW + col4 * 4] = v;
        }
    }
    __syncthreads();

    // Stage 2: 27 patches x 64 float4 each; each wave-iteration emits one
    // patch's 1 KB contiguous chunk for channel c.
    const int obase = ((b * NP * NP + py * NP) * NC + c) * 64;  // float4 units
    #pragma unroll
    for (int k = 0; k < 7; ++k) {
        const int j = t + k * TPB;
        if (j < NP * 64) {
            const int px = j >> 6;        // patch x
            const int q4 = j & 63;        // float4 within patch
            const int r  = q4 >> 2;       // patch row 0..15
            const int s  = (q4 & 3) << 2; // patch col 0,4,8,12
            const float4 v = *(const float4*)&lds[r * LDSW + px * ST + s];
            out[obase + px * (NC * 64) + q4] = v;
        }
    }
}

extern "C" void kernel_launch(void* const* d_in, const int* in_sizes, int n_in,
                              void* d_out, int out_size, void* d_ws, size_t ws_size,
                              hipStream_t stream) {
    const float4* x = (const float4*)d_in[0];
    float4* out = (float4*)d_out;
    const int grid = NB * NP * NC;   // 5184 blocks
    overlap_patch_lds<<<grid, TPB, 0, stream>>>(x, out);
}

// Round 3
// 173.540 us; speedup vs baseline: 1.1123x; 1.0016x over previous
//
#include <hip/hip_runtime.h>

// OverlapPatchEmbed: x (64,3,224,224) fp32 -> out (64,729,3,256) fp32.
// patch=16, stride=8, n=27 patches/dim.
//
// LDS-staged band kernel + XCD-aware block swizzle.
// Logical block = (b, py, c): stage the 16x224 input band in LDS
// (row stride 228 for bank spread), emit 27 overlapping patches as 1 KB
// coalesced stores per wave.
//
// Swizzle: hardware dispatches blockIdx round-robin across 8 XCDs
// (xcd = blockIdx % 8). We remap so that all 81 blocks of image b land on
// XCD b%8, consecutively: one image = 602 KB, fits the 4 MB per-XCD L2,
// so the 2x vertical read-overlap and 4x patch reuse are L2-local instead
// of bouncing through L3/HBM.

constexpr int NB  = 64;
constexpr int NC  = 3;
constexpr int HWD = 224;
constexpr int PS  = 16;   // patch size
constexpr int ST  = 8;    // stride
constexpr int NP  = 27;   // patches per dim
constexpr int ROW4 = HWD / 4;        // 56 float4 per image row
constexpr int LDSW = 228;            // LDS row stride in floats (+4 pad)
constexpr int TPB  = 256;
constexpr int BLK_PER_IMG = NP * NC; // 81
constexpr int NXCD = 8;
constexpr int IMG_PER_XCD = NB / NXCD; // 8

__global__ __launch_bounds__(TPB) void overlap_patch_lds(
    const float4* __restrict__ x, float4* __restrict__ out)
{
    // XCD-aware remap: blockIdx % 8 = XCD; keep one image's blocks on one XCD.
    const int xcd  = blockIdx.x & 7;
    const int slot = blockIdx.x >> 3;            // 0..647
    const int img_local = slot / BLK_PER_IMG;    // 0..7
    const int rest      = slot - img_local * BLK_PER_IMG; // 0..80
    const int b  = img_local * NXCD + xcd;
    const int py = rest / NC;
    const int c  = rest - py * NC;

    __shared__ float lds[PS * LDSW];   // 14592 B

    const int t = threadIdx.x;

    // Stage 1: load 16 rows x 56 float4 (896 float4), coalesced.
    const int gbase = ((b * NC + c) * HWD + py * ST) * ROW4;  // float4 units
    #pragma unroll
    for (int k = 0; k < 4; ++k) {
        const int j = t + k * TPB;
        if (j < PS * ROW4) {
            const int r    = j / ROW4;
            const int col4 = j - r * ROW4;
            const float4 v = x[gbase + j];
            *(float4*)&lds[r * LDSW + col4 * 4] = v;
        }
    }
    __syncthreads();

    // Stage 2: 27 patches x 64 float4 each; each wave-iteration emits one
    // patch's 1 KB contiguous chunk for channel c.
    const int obase = ((b * NP * NP + py * NP) * NC + c) * 64;  // float4 units
    #pragma unroll
    for (int k = 0; k < 7; ++k) {
        const int j = t + k * TPB;
        if (j < NP * 64) {
            const int px = j >> 6;        // patch x
            const int q4 = j & 63;        // float4 within patch
            const int r  = q4 >> 2;       // patch row 0..15
            const int s  = (q4 & 3) << 2; // patch col 0,4,8,12
            const float4 v = *(const float4*)&lds[r * LDSW + px * ST + s];
            out[obase + px * (NC * 64) + q4] = v;
        }
    }
}

extern "C" void kernel_launch(void* const* d_in, const int* in_sizes, int n_in,
                              void* d_out, int out_size, void* d_ws, size_t ws_size,
                              hipStream_t stream) {
    const float4* x = (const float4*)d_in[0];
    float4* out = (float4*)d_out;
    const int grid = NB * NP * NC;   // 5184 blocks = 648 * 8
    overlap_patch_lds<<<grid, TPB, 0, stream>>>(x, out);
}